// Round 8
// baseline (35.011 us; speedup 1.0000x reference)
//
#include <hip/hip_runtime.h>

#define N_STATES 12
#define MAX_OBS 50
#define TABLE_SIZE (N_STATES * MAX_OBS)  // 600 bins
#define NSUB 4                           // lane-split sub-histograms
#define SUM_BLOCKS 2048
#define SUM_THREADS 256

// d_ws layout: [0..600) table | [600..600+SUM_BLOCKS) block partials

// Kernel 1: 600-entry log-prob table in double precision.
// lp(s,o) = m*log(phi/(m+phi)) + o*log(m/(m+phi)) + lgamma(o+m) - lgamma(o+1) - lgamma(m)
__global__ void build_table_kernel(const float* __restrict__ state_means,
                                   const float* __restrict__ state_phis,
                                   float* __restrict__ table) {
    int t = blockIdx.x * blockDim.x + threadIdx.x;
    if (t >= TABLE_SIZE) return;
    int s = t / MAX_OBS;
    int o = t % MAX_OBS;
    double m  = (double)state_means[s];
    double ph = (double)state_phis[s];
    double ob = (double)o;
    double log_denom = log(m + ph);
    double log_p   = log(m)  - log_denom;
    double log_1mp = log(ph) - log_denom;
    double lp = m * log_1mp + ob * log_p
              + lgamma(ob + m) - lgamma(ob + 1.0) - lgamma(m);
    table[t] = (float)lp;
}

// Kernel 2: per-block histogram of (state,obs) into 4 lane-split LDS copies
// (copy = lane>>4), then merge + dot with table -> one partial per block.
// Hot loop: load -> addr -> ds_add (fire-and-forget, no lgkm wait).
// 2048 blocks x 256 thr = 8 blocks/CU = 32 waves/CU for max latency hiding.
__global__ void __launch_bounds__(SUM_THREADS, 8) nb_hist_kernel(const float* __restrict__ obs,
                                                                 const int* __restrict__ states,
                                                                 const float* __restrict__ table,
                                                                 float* __restrict__ partials,
                                                                 int n) {
    __shared__ unsigned int hist[NSUB * TABLE_SIZE];
    for (int i = threadIdx.x; i < NSUB * TABLE_SIZE; i += blockDim.x)
        hist[i] = 0u;
    __syncthreads();

    const int tid = blockIdx.x * blockDim.x + threadIdx.x;
    const int nthreads = gridDim.x * blockDim.x;
    const int n4 = n >> 2;
    const float4* __restrict__ obs4 = (const float4*)obs;
    const int4*  __restrict__ st4  = (const int4*)states;

    // Sub-histogram base for this lane: 16-lane groups -> distinct copies.
    unsigned int* mh = hist + ((threadIdx.x >> 4) & (NSUB - 1)) * TABLE_SIZE;

    #pragma unroll 4
    for (int i = tid; i < n4; i += nthreads) {
        float4 o = obs4[i];
        int4   s = st4[i];
        atomicAdd(&mh[s.x * MAX_OBS + (int)o.x], 1u);
        atomicAdd(&mh[s.y * MAX_OBS + (int)o.y], 1u);
        atomicAdd(&mh[s.z * MAX_OBS + (int)o.z], 1u);
        atomicAdd(&mh[s.w * MAX_OBS + (int)o.w], 1u);
    }
    for (int i = (n4 << 2) + tid; i < n; i += nthreads)
        atomicAdd(&mh[states[i] * MAX_OBS + (int)obs[i]], 1u);
    __syncthreads();

    // Merge sub-histograms and dot with table (counts exact in float).
    float acc = 0.0f;
    for (int i = threadIdx.x; i < TABLE_SIZE; i += blockDim.x) {
        unsigned int c = hist[i];
        #pragma unroll
        for (int k = 1; k < NSUB; ++k) c += hist[k * TABLE_SIZE + i];
        acc += (float)c * table[i];
    }

    // wave64 butterfly reduce
    #pragma unroll
    for (int off = 32; off > 0; off >>= 1)
        acc += __shfl_down(acc, off, 64);

    __shared__ float wsum[SUM_THREADS / 64];
    const int lane = threadIdx.x & 63;
    const int wid  = threadIdx.x >> 6;
    if (lane == 0) wsum[wid] = acc;
    __syncthreads();
    if (threadIdx.x == 0) {
        float s = 0.0f;
        #pragma unroll
        for (int w = 0; w < SUM_THREADS / 64; ++w) s += wsum[w];
        partials[blockIdx.x] = s;
    }
}

// Kernel 3: reduce SUM_BLOCKS partials -> *out. Single block, single writer.
__global__ void __launch_bounds__(256) final_reduce_kernel(const float* __restrict__ partials,
                                                           float* __restrict__ out) {
    float acc = 0.0f;
    for (int i = threadIdx.x; i < SUM_BLOCKS; i += 256)
        acc += partials[i];
    #pragma unroll
    for (int off = 32; off > 0; off >>= 1)
        acc += __shfl_down(acc, off, 64);
    __shared__ float wsum[4];
    const int lane = threadIdx.x & 63;
    const int wid  = threadIdx.x >> 6;
    if (lane == 0) wsum[wid] = acc;
    __syncthreads();
    if (threadIdx.x == 0)
        *out = wsum[0] + wsum[1] + wsum[2] + wsum[3];
}

extern "C" void kernel_launch(void* const* d_in, const int* in_sizes, int n_in,
                              void* d_out, int out_size, void* d_ws, size_t ws_size,
                              hipStream_t stream) {
    const float* obs         = (const float*)d_in[0];
    const int*   states      = (const int*)d_in[1];
    const float* state_means = (const float*)d_in[2];
    const float* state_phis  = (const float*)d_in[3];
    float* out      = (float*)d_out;
    float* table    = (float*)d_ws;
    float* partials = table + TABLE_SIZE;
    const int n = in_sizes[0];

    build_table_kernel<<<dim3((TABLE_SIZE + 255) / 256), dim3(256), 0, stream>>>(
        state_means, state_phis, table);

    nb_hist_kernel<<<dim3(SUM_BLOCKS), dim3(SUM_THREADS), 0, stream>>>(
        obs, states, table, partials, n);

    final_reduce_kernel<<<dim3(1), dim3(256), 0, stream>>>(partials, out);
}